// Round 3
// baseline (648.157 us; speedup 1.0000x reference)
//
#include <hip/hip_runtime.h>

#define NB 16
#define NC 256
#define NHW 4096
#define NDQ 32
#define NDV 128
#define NM 1024

// ---------------------------------------------------------------------------
// Kernel 1: qkv = w_qkv @ imgs (per pixel), fused 2x2 maxpool for k and v.
// Grid: (32 n-tiles of 128 px = 2 image rows, 3 o-chunks of 64, 16 batches)
// ---------------------------------------------------------------------------
__global__ __launch_bounds__(256) void qkv_pool(const float* __restrict__ imgs,
                                                const float* __restrict__ w_qkv,
                                                float* __restrict__ qbuf,
                                                float* __restrict__ kbuf,
                                                float* __restrict__ vbuf) {
    __shared__ float Xs[16][128];
    __shared__ float Ws[64][17];
    const int tid = threadIdx.x;
    const int tx = tid & 15, ty = tid >> 4;
    const int nt = blockIdx.x;   // 0..31
    const int oc = blockIdx.y;   // 0..2
    const int b  = blockIdx.z;
    const int nbase = nt * 128;  // covers image rows 2nt, 2nt+1

    float acc[4][8];
#pragma unroll
    for (int i = 0; i < 4; i++)
#pragma unroll
        for (int j = 0; j < 8; j++) acc[i][j] = 0.f;

    const int cl = tid >> 4;          // 0..15  (X stage row)
    const int nl = (tid & 15) * 8;    // 0..120 (X stage col)
    const int ol = tid >> 2;          // 0..63  (W stage row)
    const int c4 = (tid & 3) * 4;     // W stage col

    for (int cc = 0; cc < NC; cc += 16) {
        const float4* xsrc =
            (const float4*)&imgs[(size_t)(b * NC + cc + cl) * NHW + nbase + nl];
        float4 xv0 = xsrc[0];
        float4 xv1 = xsrc[1];
        *(float4*)&Xs[cl][nl]     = xv0;
        *(float4*)&Xs[cl][nl + 4] = xv1;
        float4 wv = *(const float4*)&w_qkv[(size_t)(oc * 64 + ol) * NC + cc + c4];
        Ws[ol][c4 + 0] = wv.x; Ws[ol][c4 + 1] = wv.y;
        Ws[ol][c4 + 2] = wv.z; Ws[ol][c4 + 3] = wv.w;
        __syncthreads();
#pragma unroll
        for (int kk = 0; kk < 16; kk++) {
            float4 x0 = *(const float4*)&Xs[kk][tx * 4];
            float4 x1 = *(const float4*)&Xs[kk][tx * 4 + 64];
#pragma unroll
            for (int io = 0; io < 4; io++) {
                float w = Ws[ty * 4 + io][kk];
                acc[io][0] += w * x0.x; acc[io][1] += w * x0.y;
                acc[io][2] += w * x0.z; acc[io][3] += w * x0.w;
                acc[io][4] += w * x1.x; acc[io][5] += w * x1.y;
                acc[io][6] += w * x1.z; acc[io][7] += w * x1.w;
            }
        }
        __syncthreads();
    }

    // epilogue: o_global = oc*64 + ty*4 + io
    if (oc == 0 && ty < 8) {
        // q rows (o < 32): full resolution
#pragma unroll
        for (int io = 0; io < 4; io++) {
            int o = ty * 4 + io;
            float4 s0 = make_float4(acc[io][0], acc[io][1], acc[io][2], acc[io][3]);
            float4 s1 = make_float4(acc[io][4], acc[io][5], acc[io][6], acc[io][7]);
            float* dst = &qbuf[(size_t)(b * NDQ + o) * NHW + nbase + tx * 4];
            *(float4*)dst        = s0;
            *(float4*)(dst + 64) = s1;
        }
    } else {
        // pooled k / v rows.
        // thread's 8 values: image rows 2nt (acc[.][0..3]) and 2nt+1 (acc[.][4..7]),
        // cols tx*4 + j. pooled m = nt*32 + 2tx + {0,1}
        float* arr;
        int d0, dd;
        if (oc == 0) { arr = kbuf; d0 = ty * 4 - 32;            dd = NDQ; }
        else         { arr = vbuf; d0 = (oc - 1) * 64 + ty * 4; dd = NDV; }
#pragma unroll
        for (int io = 0; io < 4; io++) {
            float p0 = fmaxf(fmaxf(acc[io][0], acc[io][1]),
                             fmaxf(acc[io][4], acc[io][5]));
            float p1 = fmaxf(fmaxf(acc[io][2], acc[io][3]),
                             fmaxf(acc[io][6], acc[io][7]));
            float* dst = &arr[(size_t)(b * dd + d0 + io) * NM + nt * 32 + tx * 2];
            dst[0] = p0;
            dst[1] = p1;
        }
    }
}

// ---------------------------------------------------------------------------
// Kernel 2: fused attention. Per (batch, 64-query tile):
//   loop over 16 KV tiles of 64 keys:
//     S[m][q] = K_tile^T Q_tile  (d=32)  -> P = exp(S) in LDS
//     acc[d][q] += V_tile x P ; den[q] += sum_m P
//   out = acc / den
// No max-subtraction: scores are O(1), exp is safe in fp32.
// ---------------------------------------------------------------------------
__global__ __launch_bounds__(256) void attention(const float* __restrict__ qbuf,
                                                 const float* __restrict__ kbuf,
                                                 const float* __restrict__ vbuf,
                                                 float* __restrict__ obuf) {
    __shared__ float Qs[32][64];
    __shared__ float Ks[32][64];
    __shared__ float Ps[64][68];
    __shared__ float Vs[128][68];
    const int tid = threadIdx.x;
    const int tx = tid & 15, ty = tid >> 4;
    const int b  = blockIdx.y;
    const int q0 = blockIdx.x * 64;

    // load Q tile: Qs[d][qi]
    {
        int d  = tid >> 3;          // 0..31
        int qi = (tid & 7) * 8;     // 0..56
        const float4* src = (const float4*)&qbuf[(size_t)(b * NDQ + d) * NHW + q0 + qi];
        *(float4*)&Qs[d][qi]     = src[0];
        *(float4*)&Qs[d][qi + 4] = src[1];
    }

    float acc[8][4];
#pragma unroll
    for (int i = 0; i < 8; i++)
#pragma unroll
        for (int j = 0; j < 4; j++) acc[i][j] = 0.f;
    float den[4] = {0.f, 0.f, 0.f, 0.f};

    for (int t = 0; t < 16; t++) {
        const int m0 = t * 64;
        {   // stage K tile: Ks[d][tm]
            int d  = tid >> 3;
            int tm = (tid & 7) * 8;
            const float4* src = (const float4*)&kbuf[(size_t)(b * NDQ + d) * NM + m0 + tm];
            *(float4*)&Ks[d][tm]     = src[0];
            *(float4*)&Ks[d][tm + 4] = src[1];
        }
        {   // stage V tile: Vs[d][tm]
            int d   = tid >> 1;
            int tmb = (tid & 1) * 32;
            const float4* src = (const float4*)&vbuf[(size_t)(b * NDV + d) * NM + m0 + tmb];
#pragma unroll
            for (int u = 0; u < 8; u++)
                *(float4*)&Vs[d][tmb + u * 4] = src[u];
        }
        __syncthreads();

        // GEMM1: S[m][q], thread owns m = tx*4..+3, q = ty*4..+3
        float s[4][4];
#pragma unroll
        for (int i = 0; i < 4; i++)
#pragma unroll
            for (int j = 0; j < 4; j++) s[i][j] = 0.f;
#pragma unroll
        for (int kk = 0; kk < 32; kk++) {
            float4 kv = *(const float4*)&Ks[kk][tx * 4];
            float4 qv = *(const float4*)&Qs[kk][ty * 4];
            float ka[4] = {kv.x, kv.y, kv.z, kv.w};
            float qa[4] = {qv.x, qv.y, qv.z, qv.w};
#pragma unroll
            for (int i = 0; i < 4; i++)
#pragma unroll
                for (int j = 0; j < 4; j++) s[i][j] += ka[i] * qa[j];
        }
        // exp -> Ps
#pragma unroll
        for (int i = 0; i < 4; i++) {
            float4 p = make_float4(__expf(s[i][0]), __expf(s[i][1]),
                                   __expf(s[i][2]), __expf(s[i][3]));
            *(float4*)&Ps[tx * 4 + i][ty * 4] = p;
        }
        __syncthreads();

        // PV over kk-quads: V read as float4 along m (b128), P as float4 along q.
        // thread owns d = 16*i + tx (i=0..7), q = ty*4..+3
#pragma unroll
        for (int kq = 0; kq < 64; kq += 4) {
            float4 pr[4];
#pragma unroll
            for (int u = 0; u < 4; u++) {
                pr[u] = *(const float4*)&Ps[kq + u][ty * 4];
                den[0] += pr[u].x; den[1] += pr[u].y;
                den[2] += pr[u].z; den[3] += pr[u].w;
            }
#pragma unroll
            for (int i = 0; i < 8; i++) {
                float4 vv = *(const float4*)&Vs[i * 16 + tx][kq];
                float va[4] = {vv.x, vv.y, vv.z, vv.w};
#pragma unroll
                for (int u = 0; u < 4; u++) {
                    acc[i][0] += va[u] * pr[u].x;
                    acc[i][1] += va[u] * pr[u].y;
                    acc[i][2] += va[u] * pr[u].z;
                    acc[i][3] += va[u] * pr[u].w;
                }
            }
        }
        __syncthreads();
    }

    float rinv[4];
#pragma unroll
    for (int j = 0; j < 4; j++) rinv[j] = 1.0f / den[j];
#pragma unroll
    for (int i = 0; i < 8; i++) {
        float4 o4 = make_float4(acc[i][0] * rinv[0], acc[i][1] * rinv[1],
                                acc[i][2] * rinv[2], acc[i][3] * rinv[3]);
        *(float4*)&obuf[(size_t)(b * NDV + i * 16 + tx) * NHW + q0 + ty * 4] = o4;
    }
}

// ---------------------------------------------------------------------------
// Kernel 3: final = imgs + scale * (w_out @ att_out)   per pixel.
// Grid: (32 n-tiles of 128, 4 c-chunks of 64, 16 batches)
// ---------------------------------------------------------------------------
__global__ __launch_bounds__(256) void outproj(const float* __restrict__ att,
                                               const float* __restrict__ w_out,
                                               const float* __restrict__ imgs,
                                               const float* __restrict__ scale_p,
                                               float* __restrict__ out) {
    __shared__ float Xs[16][128];
    __shared__ float Ws[64][17];
    const int tid = threadIdx.x;
    const int tx = tid & 15, ty = tid >> 4;
    const int nt = blockIdx.x;
    const int oc = blockIdx.y;   // 0..3 (64 channels each)
    const int b  = blockIdx.z;
    const int nbase = nt * 128;

    float acc[4][8];
#pragma unroll
    for (int i = 0; i < 4; i++)
#pragma unroll
        for (int j = 0; j < 8; j++) acc[i][j] = 0.f;

    const int cl = tid >> 4;
    const int nl = (tid & 15) * 8;
    const int ol = tid >> 2;
    const int c4 = (tid & 3) * 4;

    for (int cc = 0; cc < NDV; cc += 16) {
        const float4* xsrc =
            (const float4*)&att[(size_t)(b * NDV + cc + cl) * NHW + nbase + nl];
        float4 xv0 = xsrc[0];
        float4 xv1 = xsrc[1];
        *(float4*)&Xs[cl][nl]     = xv0;
        *(float4*)&Xs[cl][nl + 4] = xv1;
        float4 wv = *(const float4*)&w_out[(size_t)(oc * 64 + ol) * NDV + cc + c4];
        Ws[ol][c4 + 0] = wv.x; Ws[ol][c4 + 1] = wv.y;
        Ws[ol][c4 + 2] = wv.z; Ws[ol][c4 + 3] = wv.w;
        __syncthreads();
#pragma unroll
        for (int kk = 0; kk < 16; kk++) {
            float4 x0 = *(const float4*)&Xs[kk][tx * 4];
            float4 x1 = *(const float4*)&Xs[kk][tx * 4 + 64];
#pragma unroll
            for (int io = 0; io < 4; io++) {
                float w = Ws[ty * 4 + io][kk];
                acc[io][0] += w * x0.x; acc[io][1] += w * x0.y;
                acc[io][2] += w * x0.z; acc[io][3] += w * x0.w;
                acc[io][4] += w * x1.x; acc[io][5] += w * x1.y;
                acc[io][6] += w * x1.z; acc[io][7] += w * x1.w;
            }
        }
        __syncthreads();
    }

    const float sc = *scale_p;
#pragma unroll
    for (int io = 0; io < 4; io++) {
        int c = oc * 64 + ty * 4 + io;
        const float* ip = &imgs[(size_t)(b * NC + c) * NHW + nbase + tx * 4];
        float4 i0 = *(const float4*)ip;
        float4 i1 = *(const float4*)(ip + 64);
        float4 o0 = make_float4(i0.x + sc * acc[io][0], i0.y + sc * acc[io][1],
                                i0.z + sc * acc[io][2], i0.w + sc * acc[io][3]);
        float4 o1 = make_float4(i1.x + sc * acc[io][4], i1.y + sc * acc[io][5],
                                i1.z + sc * acc[io][6], i1.w + sc * acc[io][7]);
        float* dst = &out[(size_t)(b * NC + c) * NHW + nbase + tx * 4];
        *(float4*)dst        = o0;
        *(float4*)(dst + 64) = o1;
    }
}

extern "C" void kernel_launch(void* const* d_in, const int* in_sizes, int n_in,
                              void* d_out, int out_size, void* d_ws, size_t ws_size,
                              hipStream_t stream) {
    const float* imgs   = (const float*)d_in[0];
    const float* w_qkv  = (const float*)d_in[1];
    const float* w_out  = (const float*)d_in[2];
    const float* scale  = (const float*)d_in[3];
    float* out = (float*)d_out;

    float* ws   = (float*)d_ws;
    float* qbuf = ws;                                  // 16*32*4096
    float* kbuf = qbuf + (size_t)NB * NDQ * NHW;       // 16*32*1024
    float* vbuf = kbuf + (size_t)NB * NDQ * NM;        // 16*128*1024
    float* abuf = vbuf + (size_t)NB * NDV * NM;        // 16*128*4096
    // total ws use: 13,107,200 floats = 50 MiB

    hipLaunchKernelGGL(qkv_pool, dim3(32, 3, NB), dim3(256), 0, stream,
                       imgs, w_qkv, qbuf, kbuf, vbuf);
    hipLaunchKernelGGL(attention, dim3(64, NB), dim3(256), 0, stream,
                       qbuf, kbuf, vbuf, abuf);
    hipLaunchKernelGGL(outproj, dim3(32, 4, NB), dim3(256), 0, stream,
                       abuf, w_out, imgs, scale, out);
}

// Round 4
// 287.458 us; speedup vs baseline: 2.2548x; 2.2548x over previous
//
#include <hip/hip_runtime.h>

typedef __bf16 bf16;
typedef __bf16 bf16x2 __attribute__((ext_vector_type(2)));
typedef __bf16 bf16x4 __attribute__((ext_vector_type(4)));
typedef __bf16 bf16x8 __attribute__((ext_vector_type(8)));
typedef float f32x4 __attribute__((ext_vector_type(4)));

#define NB 16
#define NC 256
#define NHW 4096
#define NDQ 32
#define NDV 128
#define NM 1024

// ---------------------------------------------------------------------------
// Kernel 1: qkv = w_qkv @ imgs (fp32 GEMM core), fused 2x2 maxpool.
// Emits bf16 transposed buffers for the MFMA attention:
//   qT [b][n][32d], kT [b][m][32d], vb [b][d][1024m]
// Grid: (32 n-tiles of 128 px = 2 image rows, 3 o-chunks of 64, 16 batches)
// ---------------------------------------------------------------------------
__global__ __launch_bounds__(256) void qkv_pool(const float* __restrict__ imgs,
                                                const float* __restrict__ w_qkv,
                                                bf16* __restrict__ qT,
                                                bf16* __restrict__ kT,
                                                bf16* __restrict__ vb) {
    __shared__ float Xs[16][128];
    __shared__ float Ws[64][17];
    const int tid = threadIdx.x;
    const int tx = tid & 15, ty = tid >> 4;
    const int nt = blockIdx.x;   // 0..31
    const int oc = blockIdx.y;   // 0..2
    const int b  = blockIdx.z;
    const int nbase = nt * 128;  // covers image rows 2nt, 2nt+1

    float acc[4][8];
#pragma unroll
    for (int i = 0; i < 4; i++)
#pragma unroll
        for (int j = 0; j < 8; j++) acc[i][j] = 0.f;

    const int cl = tid >> 4;          // 0..15  (X stage row)
    const int nl = (tid & 15) * 8;    // 0..120 (X stage col)
    const int ol = tid >> 2;          // 0..63  (W stage row)
    const int c4 = (tid & 3) * 4;     // W stage col

    for (int cc = 0; cc < NC; cc += 16) {
        const float4* xsrc =
            (const float4*)&imgs[(size_t)(b * NC + cc + cl) * NHW + nbase + nl];
        float4 xv0 = xsrc[0];
        float4 xv1 = xsrc[1];
        *(float4*)&Xs[cl][nl]     = xv0;
        *(float4*)&Xs[cl][nl + 4] = xv1;
        float4 wv = *(const float4*)&w_qkv[(size_t)(oc * 64 + ol) * NC + cc + c4];
        Ws[ol][c4 + 0] = wv.x; Ws[ol][c4 + 1] = wv.y;
        Ws[ol][c4 + 2] = wv.z; Ws[ol][c4 + 3] = wv.w;
        __syncthreads();
#pragma unroll
        for (int kk = 0; kk < 16; kk++) {
            float4 x0 = *(const float4*)&Xs[kk][tx * 4];
            float4 x1 = *(const float4*)&Xs[kk][tx * 4 + 64];
#pragma unroll
            for (int io = 0; io < 4; io++) {
                float w = Ws[ty * 4 + io][kk];
                acc[io][0] += w * x0.x; acc[io][1] += w * x0.y;
                acc[io][2] += w * x0.z; acc[io][3] += w * x0.w;
                acc[io][4] += w * x1.x; acc[io][5] += w * x1.y;
                acc[io][6] += w * x1.z; acc[io][7] += w * x1.w;
            }
        }
        __syncthreads();
    }

    // epilogue: o_global = oc*64 + ty*4 + io
    if (oc == 0 && ty < 8) {
        // q rows (d = ty*4+io in 0..31): write qT[n][d], pack 4 d per store
#pragma unroll
        for (int j = 0; j < 8; j++) {
            int n = nbase + tx * 4 + (j & 3) + (j >> 2) * 64;
            bf16x4 v;
            v[0] = (bf16)acc[0][j]; v[1] = (bf16)acc[1][j];
            v[2] = (bf16)acc[2][j]; v[3] = (bf16)acc[3][j];
            *(bf16x4*)&qT[(size_t)(b * NHW + n) * NDQ + ty * 4] = v;
        }
    } else {
        // pooled values: thread covers image rows 2nt (acc[.][0..3]) and
        // 2nt+1 (acc[.][4..7]), cols tx*4+j. pooled m = nt*32 + 2tx + {0,1}
        float p0[4], p1[4];
#pragma unroll
        for (int io = 0; io < 4; io++) {
            p0[io] = fmaxf(fmaxf(acc[io][0], acc[io][1]),
                           fmaxf(acc[io][4], acc[io][5]));
            p1[io] = fmaxf(fmaxf(acc[io][2], acc[io][3]),
                           fmaxf(acc[io][6], acc[io][7]));
        }
        const int m = nt * 32 + tx * 2;
        if (oc == 0) {
            // k rows: d0 = ty*4-32 in 0..28; write kT[m][d], pack 4 d
            const int d0 = ty * 4 - 32;
            bf16x4 v0, v1;
#pragma unroll
            for (int io = 0; io < 4; io++) { v0[io] = (bf16)p0[io]; v1[io] = (bf16)p1[io]; }
            *(bf16x4*)&kT[((size_t)b * NM + m)     * NDQ + d0] = v0;
            *(bf16x4*)&kT[((size_t)b * NM + m + 1) * NDQ + d0] = v1;
        } else {
            // v rows: d = (oc-1)*64 + ty*4 + io; write vb[d][m], pack 2 m
            const int d0 = (oc - 1) * 64 + ty * 4;
#pragma unroll
            for (int io = 0; io < 4; io++) {
                bf16x2 v; v[0] = (bf16)p0[io]; v[1] = (bf16)p1[io];
                *(bf16x2*)&vb[((size_t)b * NDV + d0 + io) * NM + m] = v;
            }
        }
    }
}

// ---------------------------------------------------------------------------
// Kernel 2: bf16-MFMA fused attention. Block = 64 queries x full M loop.
// 4 waves. Per KV-step (64 keys):
//   S^T tiles via mfma(K-frag, Q-frag)  (d=32 = one MFMA per 16x16 tile)
//   P = exp(S) packed bf16x4 -> PS[n][m];  den as per-lane partials
//   PV: wave w owns d in [32w,32w+32): O[16d][16n] tiles, K=32 over m
// Epilogue: butterfly+LDS den reduce, rescale, LDS transpose, coalesced store.
// ---------------------------------------------------------------------------
__global__ __launch_bounds__(256) void attn_mfma(const bf16* __restrict__ qT,
                                                 const bf16* __restrict__ kT,
                                                 const bf16* __restrict__ vb,
                                                 float* __restrict__ obuf) {
    // LDS pool (37888 B -> 4 blocks/CU):
    //  [0,5120)      QT [64][40] bf16
    //  [5120,10240)  KT [64][40] bf16
    //  [10240,28672) VS [128][72] bf16
    //  [28672,37888) PS [64][72] bf16   (reused as den exchange at end)
    //  [0,34816)     OS [128][68] f32   (epilogue only)
    __shared__ __align__(16) char pool[37888];
    bf16* QT = (bf16*)pool;
    bf16* KT = (bf16*)(pool + 5120);
    bf16* VS = (bf16*)(pool + 10240);
    bf16* PS = (bf16*)(pool + 28672);
    float* DW = (float*)(pool + 28672);
    float* OS = (float*)pool;

    const int tid  = threadIdx.x;
    const int lane = tid & 63;
    const int w    = tid >> 6;      // wave 0..3
    const int lr   = lane & 15;     // frag row/col
    const int lg   = lane >> 4;     // k-group 0..3
    const int b    = blockIdx.y;
    const int n0   = blockIdx.x * 64;

    // ---- stage QT once: 64 rows x 32 d (4 KB, contiguous) ----
    {
        const bf16* src = qT + (size_t)(b * NHW + n0 + (tid >> 2)) * NDQ + (tid & 3) * 8;
        *(bf16x8*)&QT[(tid >> 2) * 40 + (tid & 3) * 8] = *(const bf16x8*)src;
    }
    __syncthreads();

    // hoisted Q B-frags: B[k=d][c=n], c = lr, k = lg*8+j
    bf16x8 QB[4];
#pragma unroll
    for (int nt = 0; nt < 4; nt++)
        QB[nt] = *(const bf16x8*)&QT[(nt * 16 + lr) * 40 + lg * 8];

    f32x4 zero = {0.f, 0.f, 0.f, 0.f};
    f32x4 acc[2][4];
#pragma unroll
    for (int dt = 0; dt < 2; dt++)
#pragma unroll
        for (int nt = 0; nt < 4; nt++) acc[dt][nt] = zero;
    float denp[4] = {0.f, 0.f, 0.f, 0.f};

    for (int t = 0; t < 16; t++) {
        const int m0 = t * 64;
        __syncthreads();   // protect VS/KT/PS from overwrite while prev PV reads
        // stage KT tile (4 KB contiguous)
        {
            const bf16* src = kT + (size_t)(b * NM + m0 + (tid >> 2)) * NDQ + (tid & 3) * 8;
            *(bf16x8*)&KT[(tid >> 2) * 40 + (tid & 3) * 8] = *(const bf16x8*)src;
        }
        // stage VS tile: 128 d-rows x 64 m (16 KB)
        {
            const bf16* src = vb + (size_t)(b * NDV + (tid >> 1)) * NM + m0 + (tid & 1) * 32;
            bf16* dst = &VS[(tid >> 1) * 72 + (tid & 1) * 32];
#pragma unroll
            for (int u = 0; u < 4; u++)
                *(bf16x8*)(dst + u * 8) = *(const bf16x8*)(src + u * 8);
        }
        __syncthreads();

        // ---- QK^T (swapped): wave w owns m-tile w ----
        bf16x8 ka = *(const bf16x8*)&KT[(w * 16 + lr) * 40 + lg * 8];
        f32x4 st[4];
#pragma unroll
        for (int nt = 0; nt < 4; nt++)
            st[nt] = __builtin_amdgcn_mfma_f32_16x16x32_bf16(ka, QB[nt], zero, 0, 0, 0);

        // ---- softmax piece: exp, pack, write PS[n][m] (4 consecutive m) ----
#pragma unroll
        for (int nt = 0; nt < 4; nt++) {
            float e0 = __expf(st[nt][0]);
            float e1 = __expf(st[nt][1]);
            float e2 = __expf(st[nt][2]);
            float e3 = __expf(st[nt][3]);
            denp[nt] += (e0 + e1) + (e2 + e3);
            bf16x4 pv;
            pv[0] = (bf16)e0; pv[1] = (bf16)e1; pv[2] = (bf16)e2; pv[3] = (bf16)e3;
            *(bf16x4*)&PS[(nt * 16 + lr) * 72 + (w * 16 + lg * 4)] = pv;
        }
        __syncthreads();

        // ---- PV: wave w owns d in [32w, 32w+32) ----
#pragma unroll
        for (int mc = 0; mc < 2; mc++) {
            bf16x8 pb[4];
#pragma unroll
            for (int nt = 0; nt < 4; nt++)
                pb[nt] = *(const bf16x8*)&PS[(nt * 16 + lr) * 72 + mc * 32 + lg * 8];
#pragma unroll
            for (int dt = 0; dt < 2; dt++) {
                bf16x8 va = *(const bf16x8*)&VS[(w * 32 + dt * 16 + lr) * 72 + mc * 32 + lg * 8];
#pragma unroll
                for (int nt = 0; nt < 4; nt++)
                    acc[dt][nt] = __builtin_amdgcn_mfma_f32_16x16x32_bf16(va, pb[nt], acc[dt][nt], 0, 0, 0);
            }
        }
    }
    __syncthreads();   // last PV done everywhere; PS area now reusable

    // ---- denominator reduce: intra-wave butterfly, then cross-wave via LDS ----
#pragma unroll
    for (int nt = 0; nt < 4; nt++) {
        denp[nt] += __shfl_xor(denp[nt], 16, 64);
        denp[nt] += __shfl_xor(denp[nt], 32, 64);
    }
    if (lane < 16) {
#pragma unroll
        for (int nt = 0; nt < 4; nt++) DW[(w * 4 + nt) * 16 + lane] = denp[nt];
    }
    __syncthreads();
    float rinv[4];
#pragma unroll
    for (int nt = 0; nt < 4; nt++) {
        float s = DW[(0 * 4 + nt) * 16 + lr] + DW[(1 * 4 + nt) * 16 + lr] +
                  DW[(2 * 4 + nt) * 16 + lr] + DW[(3 * 4 + nt) * 16 + lr];
        rinv[nt] = 1.0f / s;
    }
    __syncthreads();   // everyone has read DW before OS overwrites pool

    // ---- rescale + LDS transpose + coalesced store ----
#pragma unroll
    for (int dt = 0; dt < 2; dt++)
#pragma unroll
        for (int nt = 0; nt < 4; nt++)
#pragma unroll
            for (int r = 0; r < 4; r++)
                OS[(w * 32 + dt * 16 + lg * 4 + r) * 68 + nt * 16 + lr] =
                    acc[dt][nt][r] * rinv[nt];
    __syncthreads();
    {
        float* dst = &obuf[(size_t)(b * NDV + (tid >> 1)) * NHW + n0 + (tid & 1) * 32];
        const float* srcr = &OS[(tid >> 1) * 68 + (tid & 1) * 32];
#pragma unroll
        for (int u = 0; u < 8; u++)
            *(float4*)(dst + u * 4) = *(const float4*)(srcr + u * 4);
    }
}

// ---------------------------------------------------------------------------
// Kernel 3: final = imgs + scale * (w_out @ att_out)   per pixel. (fp32)
// Grid: (32 n-tiles of 128, 4 c-chunks of 64, 16 batches)
// ---------------------------------------------------------------------------
__global__ __launch_bounds__(256) void outproj(const float* __restrict__ att,
                                               const float* __restrict__ w_out,
                                               const float* __restrict__ imgs,
                                               const float* __restrict__ scale_p,
                                               float* __restrict__ out) {
    __shared__ float Xs[16][128];
    __shared__ float Ws[64][17];
    const int tid = threadIdx.x;
    const int tx = tid & 15, ty = tid >> 4;
    const int nt = blockIdx.x;
    const int oc = blockIdx.y;   // 0..3 (64 channels each)
    const int b  = blockIdx.z;
    const int nbase = nt * 128;

    float acc[4][8];
#pragma unroll
    for (int i = 0; i < 4; i++)
#pragma unroll
        for (int j = 0; j < 8; j++) acc[i][j] = 0.f;

    const int cl = tid >> 4;
    const int nl = (tid & 15) * 8;
    const int ol = tid >> 2;
    const int c4 = (tid & 3) * 4;

    for (int cc = 0; cc < NDV; cc += 16) {
        const float4* xsrc =
            (const float4*)&att[(size_t)(b * NDV + cc + cl) * NHW + nbase + nl];
        float4 xv0 = xsrc[0];
        float4 xv1 = xsrc[1];
        *(float4*)&Xs[cl][nl]     = xv0;
        *(float4*)&Xs[cl][nl + 4] = xv1;
        float4 wv = *(const float4*)&w_out[(size_t)(oc * 64 + ol) * NDV + cc + c4];
        Ws[ol][c4 + 0] = wv.x; Ws[ol][c4 + 1] = wv.y;
        Ws[ol][c4 + 2] = wv.z; Ws[ol][c4 + 3] = wv.w;
        __syncthreads();
#pragma unroll
        for (int kk = 0; kk < 16; kk++) {
            float4 x0 = *(const float4*)&Xs[kk][tx * 4];
            float4 x1 = *(const float4*)&Xs[kk][tx * 4 + 64];
#pragma unroll
            for (int io = 0; io < 4; io++) {
                float w = Ws[ty * 4 + io][kk];
                acc[io][0] += w * x0.x; acc[io][1] += w * x0.y;
                acc[io][2] += w * x0.z; acc[io][3] += w * x0.w;
                acc[io][4] += w * x1.x; acc[io][5] += w * x1.y;
                acc[io][6] += w * x1.z; acc[io][7] += w * x1.w;
            }
        }
        __syncthreads();
    }

    const float sc = *scale_p;
#pragma unroll
    for (int io = 0; io < 4; io++) {
        int c = oc * 64 + ty * 4 + io;
        const float* ip = &imgs[(size_t)(b * NC + c) * NHW + nbase + tx * 4];
        float4 i0 = *(const float4*)ip;
        float4 i1 = *(const float4*)(ip + 64);
        float4 o0 = make_float4(i0.x + sc * acc[io][0], i0.y + sc * acc[io][1],
                                i0.z + sc * acc[io][2], i0.w + sc * acc[io][3]);
        float4 o1 = make_float4(i1.x + sc * acc[io][4], i1.y + sc * acc[io][5],
                                i1.z + sc * acc[io][6], i1.w + sc * acc[io][7]);
        float* dst = &out[(size_t)(b * NC + c) * NHW + nbase + tx * 4];
        *(float4*)dst        = o0;
        *(float4*)(dst + 64) = o1;
    }
}

extern "C" void kernel_launch(void* const* d_in, const int* in_sizes, int n_in,
                              void* d_out, int out_size, void* d_ws, size_t ws_size,
                              hipStream_t stream) {
    const float* imgs   = (const float*)d_in[0];
    const float* w_qkv  = (const float*)d_in[1];
    const float* w_out  = (const float*)d_in[2];
    const float* scale  = (const float*)d_in[3];
    float* out = (float*)d_out;

    char* wsb = (char*)d_ws;
    bf16*  qTg  = (bf16*)(wsb);                 // 16*4096*32*2B = 4 MiB
    bf16*  kTg  = (bf16*)(wsb + (4u << 20));    // 16*1024*32*2B = 1 MiB
    bf16*  vbg  = (bf16*)(wsb + (5u << 20));    // 16*128*1024*2B = 4 MiB
    float* abuf = (float*)(wsb + (9u << 20));   // 16*128*4096*4B = 32 MiB

    hipLaunchKernelGGL(qkv_pool, dim3(32, 3, NB), dim3(256), 0, stream,
                       imgs, w_qkv, qTg, kTg, vbg);
    hipLaunchKernelGGL(attn_mfma, dim3(64, NB), dim3(256), 0, stream,
                       qTg, kTg, vbg, abuf);
    hipLaunchKernelGGL(outproj, dim3(32, 4, NB), dim3(256), 0, stream,
                       abuf, w_out, imgs, scale, out);
}

// Round 5
// 181.870 us; speedup vs baseline: 3.5638x; 1.5806x over previous
//
#include <hip/hip_runtime.h>

typedef __bf16 bf16;
typedef __bf16 bf16x2 __attribute__((ext_vector_type(2)));
typedef __bf16 bf16x4 __attribute__((ext_vector_type(4)));
typedef __bf16 bf16x8 __attribute__((ext_vector_type(8)));
typedef float f32x4 __attribute__((ext_vector_type(4)));

#define NB 16
#define NC 256
#define NHW 4096
#define NDQ 32
#define NDV 128
#define NM 1024

// ---------------------------------------------------------------------------
// Kernel 0: convert w_qkv (192x256) and w_out (256x128) fp32 -> bf16 once.
// Grid: 40 blocks x 256 thr, 8 elems/thread.
// ---------------------------------------------------------------------------
__global__ __launch_bounds__(256) void cvt_weights(const float* __restrict__ wq,
                                                   const float* __restrict__ wo,
                                                   bf16* __restrict__ wq16,
                                                   bf16* __restrict__ wo16) {
    int idx = blockIdx.x * 256 + threadIdx.x;
    const float* src;
    bf16* dst;
    int base;
    if (idx < 6144) { src = wq; dst = wq16; base = idx; }       // 6144*8 = 49152
    else            { src = wo; dst = wo16; base = idx - 6144; } // 4096*8 = 32768
    float4 a = ((const float4*)src)[base * 2];
    float4 c = ((const float4*)src)[base * 2 + 1];
    bf16x8 v;
    v[0] = (bf16)a.x; v[1] = (bf16)a.y; v[2] = (bf16)a.z; v[3] = (bf16)a.w;
    v[4] = (bf16)c.x; v[5] = (bf16)c.y; v[6] = (bf16)c.z; v[7] = (bf16)c.w;
    *(bf16x8*)&dst[base * 8] = v;
}

// ---------------------------------------------------------------------------
// Kernel 1: qkv = w_qkv @ imgs via bf16 MFMA, fused 2x2 maxpool for k,v.
// Block: 192 o x 128 n (2 image rows), K=256 in 4 chunks of 64.
// 4 waves, wave w owns o in [48w, 48w+48) (3 o-tiles) x all 8 n-tiles.
// LDS: XS[128n][64c] + WS[192o][64c], bf16, XOR-swizzled (slot ^= row&7).
// Outputs: qT[b][n][32d], kT[b][m][32d], vb[b][d][1024m]  (all bf16)
// ---------------------------------------------------------------------------
__global__ __launch_bounds__(256) void qkv_mfma(const float* __restrict__ imgs,
                                                const bf16* __restrict__ wq16,
                                                bf16* __restrict__ qT,
                                                bf16* __restrict__ kT,
                                                bf16* __restrict__ vb) {
    __shared__ __align__(16) char lds[40960];
    bf16* XS = (bf16*)lds;             // [128][64] swizzled, 16 KB
    bf16* WS = (bf16*)(lds + 16384);   // [192][64] swizzled, 24 KB

    const int tid  = threadIdx.x;
    const int lane = tid & 63;
    const int w    = tid >> 6;
    const int lr   = lane & 15;
    const int lg   = lane >> 4;
    const int bx   = blockIdx.x;       // 0..31 (n-tile = image rows 2bx,2bx+1)
    const int b    = blockIdx.y;
    const int n0   = bx * 128;

    f32x4 acc[3][8];
#pragma unroll
    for (int i = 0; i < 3; i++)
#pragma unroll
        for (int j = 0; j < 8; j++) acc[i][j] = (f32x4){0.f, 0.f, 0.f, 0.f};

    const int snl = tid & 63;          // staging n within 64-group
    const int scg = (tid >> 6) * 8;    // staging c-group base

    for (int kc = 0; kc < 4; kc++) {
        if (kc) __syncthreads();
        // ---- stage X: imgs[kc*64..+64 c][n0..+128] -> XS[n][c] bf16 swz ----
#pragma unroll
        for (int j = 0; j < 4; j++) {
            int n  = snl + (j & 1) * 64;
            int c8 = scg + (j >> 1) * 32;
            const float* g = imgs + (size_t)(b * NC + kc * 64 + c8) * NHW + n0 + n;
            bf16x8 v;
#pragma unroll
            for (int i = 0; i < 8; i++) v[i] = (bf16)g[i * NHW];
            *(bf16x8*)(XS + n * 64 + ((((c8 >> 3) ^ (n & 7))) << 3)) = v;
        }
        // ---- stage W: wq16[o][kc*64..+64] -> WS[o][c] swz ----
#pragma unroll
        for (int j = 0; j < 6; j++) {
            int idx = j * 256 + tid;      // 0..1535
            int o = idx >> 3, s = idx & 7;
            bf16x8 v = *(const bf16x8*)(wq16 + (size_t)o * NC + kc * 64 + s * 8);
            *(bf16x8*)(WS + o * 64 + ((s ^ (o & 7)) << 3)) = v;
        }
        __syncthreads();
        // ---- compute: 2 sub-k of 32 ----
#pragma unroll
        for (int sub = 0; sub < 2; sub++) {
            bf16x8 af[3], bfr[8];
#pragma unroll
            for (int ot = 0; ot < 3; ot++) {
                int o = w * 48 + ot * 16 + lr;
                af[ot] = *(const bf16x8*)(WS + o * 64 + (((sub * 4 + lg) ^ (o & 7)) << 3));
            }
#pragma unroll
            for (int nt = 0; nt < 8; nt++) {
                int n = nt * 16 + lr;
                bfr[nt] = *(const bf16x8*)(XS + n * 64 + (((sub * 4 + lg) ^ (n & 7)) << 3));
            }
#pragma unroll
            for (int ot = 0; ot < 3; ot++)
#pragma unroll
                for (int nt = 0; nt < 8; nt++)
                    acc[ot][nt] = __builtin_amdgcn_mfma_f32_16x16x32_bf16(af[ot], bfr[nt], acc[ot][nt], 0, 0, 0);
        }
    }

    // ---- epilogue: lane holds o = w*48+ot*16+lg*4+r, n = nt*16+lr ----
#pragma unroll
    for (int ot = 0; ot < 3; ot++) {
        const int o_base = w * 48 + ot * 16;
        if (o_base < 32) {
            // q: full resolution, d = o
            const int d0 = o_base + lg * 4;
#pragma unroll
            for (int nt = 0; nt < 8; nt++) {
                int n = n0 + nt * 16 + lr;
                bf16x4 v;
#pragma unroll
                for (int r = 0; r < 4; r++) v[r] = (bf16)acc[ot][nt][r];
                *(bf16x4*)&qT[((size_t)b * NHW + n) * NDQ + d0] = v;
            }
        } else {
            // pooled: rows pair (nt, nt+4), cols pair via shfl_xor(1)
            float pm[4][4];
#pragma unroll
            for (int ntg = 0; ntg < 4; ntg++)
#pragma unroll
                for (int r = 0; r < 4; r++) {
                    float v0 = fmaxf(acc[ot][ntg][r], acc[ot][ntg + 4][r]);
                    float v1 = __shfl_xor(v0, 1, 64);
                    pm[ntg][r] = fmaxf(v0, v1);
                }
            if (!(lr & 1)) {
                if (o_base < 64) {
                    const int d0 = o_base - 32 + lg * 4;
#pragma unroll
                    for (int ntg = 0; ntg < 4; ntg++) {
                        int m = bx * 32 + ((ntg * 16 + lr) >> 1);
                        bf16x4 v;
#pragma unroll
                        for (int r = 0; r < 4; r++) v[r] = (bf16)pm[ntg][r];
                        *(bf16x4*)&kT[((size_t)b * NM + m) * NDQ + d0] = v;
                    }
                } else {
                    const int dv0 = o_base - 64 + lg * 4;
#pragma unroll
                    for (int ntg = 0; ntg < 4; ntg++) {
                        int m = bx * 32 + ((ntg * 16 + lr) >> 1);
#pragma unroll
                        for (int r = 0; r < 4; r++)
                            vb[((size_t)b * NDV + dv0 + r) * NM + m] = (bf16)pm[ntg][r];
                    }
                }
            }
        }
    }
}

// ---------------------------------------------------------------------------
// Kernel 2: bf16-MFMA fused attention (validated core from round 4).
// Epilogue now writes aT[b][n][128d] bf16 directly (no LDS transpose).
// ---------------------------------------------------------------------------
__global__ __launch_bounds__(256) void attn_mfma(const bf16* __restrict__ qT,
                                                 const bf16* __restrict__ kT,
                                                 const bf16* __restrict__ vb,
                                                 bf16* __restrict__ aT) {
    __shared__ __align__(16) char pool[37888];
    bf16* QT = (bf16*)pool;            // [64][40]
    bf16* KT = (bf16*)(pool + 5120);   // [64][40]
    bf16* VS = (bf16*)(pool + 10240);  // [128][72]
    bf16* PS = (bf16*)(pool + 28672);  // [64][72]
    float* DW = (float*)(pool + 28672);

    const int tid  = threadIdx.x;
    const int lane = tid & 63;
    const int w    = tid >> 6;
    const int lr   = lane & 15;
    const int lg   = lane >> 4;
    const int b    = blockIdx.y;
    const int n0   = blockIdx.x * 64;

    {
        const bf16* src = qT + (size_t)(b * NHW + n0 + (tid >> 2)) * NDQ + (tid & 3) * 8;
        *(bf16x8*)&QT[(tid >> 2) * 40 + (tid & 3) * 8] = *(const bf16x8*)src;
    }
    __syncthreads();

    bf16x8 QB[4];
#pragma unroll
    for (int nt = 0; nt < 4; nt++)
        QB[nt] = *(const bf16x8*)&QT[(nt * 16 + lr) * 40 + lg * 8];

    f32x4 zero = {0.f, 0.f, 0.f, 0.f};
    f32x4 acc[2][4];
#pragma unroll
    for (int dt = 0; dt < 2; dt++)
#pragma unroll
        for (int nt = 0; nt < 4; nt++) acc[dt][nt] = zero;
    float denp[4] = {0.f, 0.f, 0.f, 0.f};

    for (int t = 0; t < 16; t++) {
        const int m0 = t * 64;
        __syncthreads();
        {
            const bf16* src = kT + (size_t)(b * NM + m0 + (tid >> 2)) * NDQ + (tid & 3) * 8;
            *(bf16x8*)&KT[(tid >> 2) * 40 + (tid & 3) * 8] = *(const bf16x8*)src;
        }
        {
            const bf16* src = vb + (size_t)(b * NDV + (tid >> 1)) * NM + m0 + (tid & 1) * 32;
            bf16* dst = &VS[(tid >> 1) * 72 + (tid & 1) * 32];
#pragma unroll
            for (int u = 0; u < 4; u++)
                *(bf16x8*)(dst + u * 8) = *(const bf16x8*)(src + u * 8);
        }
        __syncthreads();

        bf16x8 ka = *(const bf16x8*)&KT[(w * 16 + lr) * 40 + lg * 8];
        f32x4 st[4];
#pragma unroll
        for (int nt = 0; nt < 4; nt++)
            st[nt] = __builtin_amdgcn_mfma_f32_16x16x32_bf16(ka, QB[nt], zero, 0, 0, 0);

#pragma unroll
        for (int nt = 0; nt < 4; nt++) {
            float e0 = __expf(st[nt][0]);
            float e1 = __expf(st[nt][1]);
            float e2 = __expf(st[nt][2]);
            float e3 = __expf(st[nt][3]);
            denp[nt] += (e0 + e1) + (e2 + e3);
            bf16x4 pv;
            pv[0] = (bf16)e0; pv[1] = (bf16)e1; pv[2] = (bf16)e2; pv[3] = (bf16)e3;
            *(bf16x4*)&PS[(nt * 16 + lr) * 72 + (w * 16 + lg * 4)] = pv;
        }
        __syncthreads();

#pragma unroll
        for (int mc = 0; mc < 2; mc++) {
            bf16x8 pb[4];
#pragma unroll
            for (int nt = 0; nt < 4; nt++)
                pb[nt] = *(const bf16x8*)&PS[(nt * 16 + lr) * 72 + mc * 32 + lg * 8];
#pragma unroll
            for (int dt = 0; dt < 2; dt++) {
                bf16x8 va = *(const bf16x8*)&VS[(w * 32 + dt * 16 + lr) * 72 + mc * 32 + lg * 8];
#pragma unroll
                for (int nt = 0; nt < 4; nt++)
                    acc[dt][nt] = __builtin_amdgcn_mfma_f32_16x16x32_bf16(va, pb[nt], acc[dt][nt], 0, 0, 0);
            }
        }
    }
    __syncthreads();

    // denominator reduce
#pragma unroll
    for (int nt = 0; nt < 4; nt++) {
        denp[nt] += __shfl_xor(denp[nt], 16, 64);
        denp[nt] += __shfl_xor(denp[nt], 32, 64);
    }
    if (lane < 16) {
#pragma unroll
        for (int nt = 0; nt < 4; nt++) DW[(w * 4 + nt) * 16 + lane] = denp[nt];
    }
    __syncthreads();
    float rinv[4];
#pragma unroll
    for (int nt = 0; nt < 4; nt++) {
        float s = DW[(0 * 4 + nt) * 16 + lr] + DW[(1 * 4 + nt) * 16 + lr] +
                  DW[(2 * 4 + nt) * 16 + lr] + DW[(3 * 4 + nt) * 16 + lr];
        rinv[nt] = 1.0f / s;
    }

    // direct transposed store: lane holds d = w*32+dt*16+lg*4+r, n = nt*16+lr
#pragma unroll
    for (int dt = 0; dt < 2; dt++)
#pragma unroll
        for (int nt = 0; nt < 4; nt++) {
            int d0 = w * 32 + dt * 16 + lg * 4;
            int n  = n0 + nt * 16 + lr;
            bf16x4 v;
#pragma unroll
            for (int r = 0; r < 4; r++) v[r] = (bf16)(acc[dt][nt][r] * rinv[nt]);
            *(bf16x4*)&aT[((size_t)b * NHW + n) * NDV + d0] = v;
        }
}

// ---------------------------------------------------------------------------
// Kernel 3: out = imgs + scale * (w_out @ att) via bf16 MFMA.
// Block: 128 c x 128 n, K=128 staged once. Grid (32 n-tiles, 2 c-halves, 16 b).
// LDS: XS[128n][128d] + WS[128c][128d] bf16, swizzled (slot ^= row&15).
// ---------------------------------------------------------------------------
__global__ __launch_bounds__(256) void outproj_mfma(const bf16* __restrict__ aT,
                                                    const bf16* __restrict__ wo16,
                                                    const float* __restrict__ imgs,
                                                    const float* __restrict__ scale_p,
                                                    float* __restrict__ out) {
    __shared__ __align__(16) char lds[65536];
    bf16* XS = (bf16*)lds;             // [128][128] swz, 32 KB
    bf16* WS = (bf16*)(lds + 32768);   // [128][128] swz, 32 KB

    const int tid  = threadIdx.x;
    const int lane = tid & 63;
    const int w    = tid >> 6;
    const int lr   = lane & 15;
    const int lg   = lane >> 4;
    const int wr   = w >> 1, wc = w & 1;
    const int bx   = blockIdx.x;
    const int ch   = blockIdx.y;
    const int b    = blockIdx.z;
    const int n0   = bx * 128;

    // stage both operands (16 slots/row, 8 slot-loads each per thread)
#pragma unroll
    for (int j = 0; j < 8; j++) {
        int idx = j * 256 + tid;          // 0..2047
        int row = idx >> 4, s = idx & 15;
        int sw  = ((s ^ (row & 15)) << 3);
        *(bf16x8*)(XS + row * 128 + sw) =
            *(const bf16x8*)(aT + ((size_t)b * NHW + n0 + row) * NDV + s * 8);
        *(bf16x8*)(WS + row * 128 + sw) =
            *(const bf16x8*)(wo16 + (size_t)(ch * 128 + row) * NDV + s * 8);
    }
    __syncthreads();

    f32x4 acc[4][4];
#pragma unroll
    for (int i = 0; i < 4; i++)
#pragma unroll
        for (int j = 0; j < 4; j++) acc[i][j] = (f32x4){0.f, 0.f, 0.f, 0.f};

#pragma unroll
    for (int kk = 0; kk < 4; kk++) {
        bf16x8 af[4], bfr[4];
#pragma unroll
        for (int ot = 0; ot < 4; ot++) {
            int c = wr * 64 + ot * 16 + lr;
            af[ot] = *(const bf16x8*)(WS + c * 128 + (((kk * 4 + lg) ^ (c & 15)) << 3));
        }
#pragma unroll
        for (int nt = 0; nt < 4; nt++) {
            int n = wc * 64 + nt * 16 + lr;
            bfr[nt] = *(const bf16x8*)(XS + n * 128 + (((kk * 4 + lg) ^ (n & 15)) << 3));
        }
#pragma unroll
        for (int ot = 0; ot < 4; ot++)
#pragma unroll
            for (int nt = 0; nt < 4; nt++)
                acc[ot][nt] = __builtin_amdgcn_mfma_f32_16x16x32_bf16(af[ot], bfr[nt], acc[ot][nt], 0, 0, 0);
    }

    const float sc = *scale_p;
#pragma unroll
    for (int ot = 0; ot < 4; ot++)
#pragma unroll
        for (int nt = 0; nt < 4; nt++) {
            int n = n0 + wc * 64 + nt * 16 + lr;
#pragma unroll
            for (int r = 0; r < 4; r++) {
                int c = ch * 128 + wr * 64 + ot * 16 + lg * 4 + r;
                size_t off = ((size_t)b * NC + c) * NHW + n;
                out[off] = imgs[off] + sc * acc[ot][nt][r];
            }
        }
}

extern "C" void kernel_launch(void* const* d_in, const int* in_sizes, int n_in,
                              void* d_out, int out_size, void* d_ws, size_t ws_size,
                              hipStream_t stream) {
    const float* imgs  = (const float*)d_in[0];
    const float* w_qkv = (const float*)d_in[1];
    const float* w_out = (const float*)d_in[2];
    const float* scale = (const float*)d_in[3];
    float* out = (float*)d_out;

    char* wsb = (char*)d_ws;
    bf16* aTg  = (bf16*)(wsb);                       // 16*4096*128*2 = 16 MiB
    bf16* qTg  = (bf16*)(wsb + (16u << 20));         // 4 MiB
    bf16* kTg  = (bf16*)(wsb + (20u << 20));         // 1 MiB
    bf16* vbg  = (bf16*)(wsb + (21u << 20));         // 4 MiB
    bf16* wq16 = (bf16*)(wsb + (25u << 20));         // 96 KiB
    bf16* wo16 = (bf16*)(wsb + (25u << 20) + 98304); // 64 KiB

    hipLaunchKernelGGL(cvt_weights, dim3(40), dim3(256), 0, stream,
                       w_qkv, w_out, wq16, wo16);
    hipLaunchKernelGGL(qkv_mfma, dim3(32, NB), dim3(256), 0, stream,
                       imgs, wq16, qTg, kTg, vbg);
    hipLaunchKernelGGL(attn_mfma, dim3(64, NB), dim3(256), 0, stream,
                       qTg, kTg, vbg, aTg);
    hipLaunchKernelGGL(outproj_mfma, dim3(32, 2, NB), dim3(256), 0, stream,
                       aTg, wo16, imgs, scale, out);
}